// Round 1
// baseline (2337.098 us; speedup 1.0000x reference)
//
#include <hip/hip_runtime.h>

#define P_TOT 65536
#define DIM   384
#define KCL   64
#define ITERS 10
#define BPTS  256          // points per block (fused / final)
#define BK    16           // k-tile depth
#define NKT   (DIM / BK)   // 24
#define LDA   264          // padded A-tile row (points), 16B-aligned rows
#define LDB   72           // padded B-tile row (clusters), 16B-aligned rows

// d_ws layout (floats): centers[24576] | sums[24576] | cnorm[64] | cnt[64] | CW[24576]

// centers0 = points[:64]; cnorm[c] = ||center||^2 ; zero sums/cnt
__global__ __launch_bounds__(384) void init_kernel(const float* __restrict__ x,
                                                   float* __restrict__ centers,
                                                   float* __restrict__ sums,
                                                   float* __restrict__ cnorm,
                                                   float* __restrict__ cnt) {
    __shared__ float red[384];
    const int c = blockIdx.x, t = threadIdx.x;
    float v = x[(size_t)c * DIM + t];
    centers[(size_t)c * DIM + t] = v;
    sums[(size_t)c * DIM + t] = 0.f;
    if (t == 0) cnt[c] = 0.f;
    red[t] = v * v;
    __syncthreads();
    if (t < 128) red[t] = red[t] + red[t + 128] + red[t + 256];
    __syncthreads();
    for (int s = 64; s > 0; s >>= 1) {
        if (t < s) red[t] += red[t + s];
        __syncthreads();
    }
    if (t == 0) cnorm[c] = red[0];
}

// Fused assign + accumulate: one x pass per k-means iteration.
// Phase A: 256 points x 64 clusters GEMM (4pt x 8cl per thread), argmin -> lab[] in LDS.
// Phase B: dim-sliced accumulation into 96KB LDS sum table via ds_add_f32 (conflict-free).
__global__ __launch_bounds__(512) void fused_kernel(const float* __restrict__ x,
                                                    const float* __restrict__ centers,
                                                    const float* __restrict__ cnorm,
                                                    float* __restrict__ sums,
                                                    float* __restrict__ cnt) {
    __shared__ float lsum[KCL * DIM];     // 96 KB
    __shared__ float At[BK][LDA];         // 16.9 KB, transposed [k][point]
    __shared__ float Bt[BK][LDB];         // 4.6 KB,  transposed [k][cluster]
    __shared__ float rv[BPTS][9];         // pad 9: gcd(9,32)=1 -> conflict-free reduce
    __shared__ int   rc[BPTS][9];
    __shared__ int   lab[BPTS];
    __shared__ int   lcnt[KCL];
    __shared__ float scn[KCL];

    const int t   = threadIdx.x;
    const int cg  = t & 7;          // cluster group: clusters cg*8..cg*8+7
    const int pg  = t >> 3;         // point group:   points  pg*4..pg*4+3
    const int p0  = blockIdx.x * BPTS;
    const int sp  = t >> 1;         // A-staging: point row 0..255
    const int sk  = (t & 1) * 8;    // A-staging: k offset {0,8}
    const int sc  = t >> 2;         // B-staging: cluster 0..63 (t<256)
    const int sck = (t & 3) * 4;    // B-staging: k offset {0,4,8,12}

    for (int i = t; i < KCL * DIM; i += 512) lsum[i] = 0.f;
    if (t < KCL) { lcnt[t] = 0; scn[t] = cnorm[t]; }

    float acc[4][8];
#pragma unroll
    for (int i = 0; i < 4; ++i)
#pragma unroll
        for (int j = 0; j < 8; ++j) acc[i][j] = 0.f;

    const float* xrow = x + (size_t)(p0 + sp) * DIM;
    const float* crow = centers + (size_t)sc * DIM;

    // prefetch tile 0 into registers
    float4 ra0 = *(const float4*)(xrow + sk);
    float4 ra1 = *(const float4*)(xrow + sk + 4);
    float4 rb  = make_float4(0.f, 0.f, 0.f, 0.f);
    if (t < 256) rb = *(const float4*)(crow + sck);

    for (int kt = 0; kt < NKT; ++kt) {
        __syncthreads();
        At[sk + 0][sp] = ra0.x; At[sk + 1][sp] = ra0.y;
        At[sk + 2][sp] = ra0.z; At[sk + 3][sp] = ra0.w;
        At[sk + 4][sp] = ra1.x; At[sk + 5][sp] = ra1.y;
        At[sk + 6][sp] = ra1.z; At[sk + 7][sp] = ra1.w;
        if (t < 256) {
            Bt[sck + 0][sc] = rb.x; Bt[sck + 1][sc] = rb.y;
            Bt[sck + 2][sc] = rb.z; Bt[sck + 3][sc] = rb.w;
        }
        if (kt + 1 < NKT) {   // prefetch next tile; latency hides under kk-loop
            const int k0 = (kt + 1) * BK;
            ra0 = *(const float4*)(xrow + k0 + sk);
            ra1 = *(const float4*)(xrow + k0 + sk + 4);
            if (t < 256) rb = *(const float4*)(crow + k0 + sck);
        }
        __syncthreads();
#pragma unroll
        for (int kk = 0; kk < BK; ++kk) {
            float4 a4 = *(const float4*)&At[kk][pg * 4];
            float4 b0 = *(const float4*)&Bt[kk][cg * 8];
            float4 b1 = *(const float4*)&Bt[kk][cg * 8 + 4];
            const float av[4] = {a4.x, a4.y, a4.z, a4.w};
            const float bv[8] = {b0.x, b0.y, b0.z, b0.w, b1.x, b1.y, b1.z, b1.w};
#pragma unroll
            for (int i = 0; i < 4; ++i)
#pragma unroll
                for (int j = 0; j < 8; ++j) acc[i][j] += av[i] * bv[j];
        }
    }

#pragma unroll
    for (int i = 0; i < 4; ++i) {
        float bvv = 3.4e38f; int bc = 0;
#pragma unroll
        for (int j = 0; j < 8; ++j) {
            float d = scn[cg * 8 + j] - 2.0f * acc[i][j];
            if (d < bvv) { bvv = d; bc = cg * 8 + j; }  // strict <: lowest idx wins
        }
        rv[pg * 4 + i][cg] = bvv;
        rc[pg * 4 + i][cg] = bc;
    }
    __syncthreads();
    if (t < BPTS) {
        float bvv = rv[t][0]; int bc = rc[t][0];
#pragma unroll
        for (int g = 1; g < 8; ++g) {   // ascending cg: lowest cluster wins ties
            float v = rv[t][g];
            if (v < bvv) { bvv = v; bc = rc[t][g]; }
        }
        lab[t] = bc;
        atomicAdd(&lcnt[bc], 1);
    }
    __syncthreads();

    // Phase B: 4 point-subsets x 128 dim-slots; lanes hit consecutive banks.
    {
        const int ss = t >> 7;      // 0..3 (wave-uniform)
        const int dd = t & 127;     // 0..127
#pragma unroll 4
        for (int r = 0; r < 64; ++r) {
            const int p = r * 4 + ss;
            const float* xp = x + (size_t)(p0 + p) * DIM;
            float* ls = &lsum[lab[p] * DIM];
            atomicAdd(&ls[dd], xp[dd]);
            atomicAdd(&ls[dd + 128], xp[dd + 128]);
            atomicAdd(&ls[dd + 256], xp[dd + 256]);
        }
    }
    __syncthreads();
    for (int i = t; i < KCL * DIM; i += 512) {
        float v = lsum[i];
        if (v != 0.f) atomicAdd(&sums[i], v);
    }
    if (t < KCL && lcnt[t] > 0) atomicAdd(&cnt[t], (float)lcnt[t]);
}

// centers[c] = cnt>0 ? sums/cnt : old ; cnorm ; re-zero sums/cnt for next iter
__global__ __launch_bounds__(384) void update_kernel(float* __restrict__ sums,
                                                     float* __restrict__ cnt,
                                                     float* __restrict__ centers,
                                                     float* __restrict__ cnorm) {
    __shared__ float red[384];
    const int c = blockIdx.x, t = threadIdx.x;
    float s = sums[(size_t)c * DIM + t];
    float n = cnt[c];
    float oldv = centers[(size_t)c * DIM + t];
    float nc = (n > 0.f) ? (s / n) : oldv;
    centers[(size_t)c * DIM + t] = nc;
    sums[(size_t)c * DIM + t] = 0.f;
    if (t == 0) cnt[c] = 0.f;
    red[t] = nc * nc;
    __syncthreads();
    if (t < 128) red[t] = red[t] + red[t + 128] + red[t + 256];
    __syncthreads();
    for (int st = 64; st > 0; st >>= 1) {
        if (t < st) red[t] += red[t + st];
        __syncthreads();
    }
    if (t == 0) cnorm[c] = red[0];
}

// CW[c][j] = b[j] + sum_d centers[c][d] * W[j][d]
__global__ __launch_bounds__(384) void cw_kernel(const float* __restrict__ centers,
                                                 const float* __restrict__ W,
                                                 const float* __restrict__ b,
                                                 float* __restrict__ CW) {
    __shared__ float cs[DIM];
    const int c = blockIdx.x, j = threadIdx.x;
    cs[j] = centers[(size_t)c * DIM + j];
    __syncthreads();
    float acc = b[j];
    const float* wr = W + (size_t)j * DIM;
    for (int d4 = 0; d4 < 96; ++d4) {
        float4 v = *(const float4*)(wr + d4 * 4);
        acc += cs[d4 * 4 + 0] * v.x + cs[d4 * 4 + 1] * v.y
             + cs[d4 * 4 + 2] * v.z + cs[d4 * 4 + 3] * v.w;
    }
    CW[(size_t)c * DIM + j] = acc;
}

// final: same GEMM/argmin schedule, then out[p][:] = CW[label[p]][:]
__global__ __launch_bounds__(512) void final_kernel(const float* __restrict__ x,
                                                    const float* __restrict__ centers,
                                                    const float* __restrict__ cnorm,
                                                    const float* __restrict__ CW,
                                                    float* __restrict__ out) {
    __shared__ float At[BK][LDA];
    __shared__ float Bt[BK][LDB];
    __shared__ float rv[BPTS][9];
    __shared__ int   rc[BPTS][9];
    __shared__ int   lab[BPTS];
    __shared__ float scn[KCL];

    const int t   = threadIdx.x;
    const int cg  = t & 7;
    const int pg  = t >> 3;
    const int p0  = blockIdx.x * BPTS;
    const int sp  = t >> 1;
    const int sk  = (t & 1) * 8;
    const int sc  = t >> 2;
    const int sck = (t & 3) * 4;

    if (t < KCL) scn[t] = cnorm[t];

    float acc[4][8];
#pragma unroll
    for (int i = 0; i < 4; ++i)
#pragma unroll
        for (int j = 0; j < 8; ++j) acc[i][j] = 0.f;

    const float* xrow = x + (size_t)(p0 + sp) * DIM;
    const float* crow = centers + (size_t)sc * DIM;

    float4 ra0 = *(const float4*)(xrow + sk);
    float4 ra1 = *(const float4*)(xrow + sk + 4);
    float4 rb  = make_float4(0.f, 0.f, 0.f, 0.f);
    if (t < 256) rb = *(const float4*)(crow + sck);

    for (int kt = 0; kt < NKT; ++kt) {
        __syncthreads();
        At[sk + 0][sp] = ra0.x; At[sk + 1][sp] = ra0.y;
        At[sk + 2][sp] = ra0.z; At[sk + 3][sp] = ra0.w;
        At[sk + 4][sp] = ra1.x; At[sk + 5][sp] = ra1.y;
        At[sk + 6][sp] = ra1.z; At[sk + 7][sp] = ra1.w;
        if (t < 256) {
            Bt[sck + 0][sc] = rb.x; Bt[sck + 1][sc] = rb.y;
            Bt[sck + 2][sc] = rb.z; Bt[sck + 3][sc] = rb.w;
        }
        if (kt + 1 < NKT) {
            const int k0 = (kt + 1) * BK;
            ra0 = *(const float4*)(xrow + k0 + sk);
            ra1 = *(const float4*)(xrow + k0 + sk + 4);
            if (t < 256) rb = *(const float4*)(crow + k0 + sck);
        }
        __syncthreads();
#pragma unroll
        for (int kk = 0; kk < BK; ++kk) {
            float4 a4 = *(const float4*)&At[kk][pg * 4];
            float4 b0 = *(const float4*)&Bt[kk][cg * 8];
            float4 b1 = *(const float4*)&Bt[kk][cg * 8 + 4];
            const float av[4] = {a4.x, a4.y, a4.z, a4.w};
            const float bv[8] = {b0.x, b0.y, b0.z, b0.w, b1.x, b1.y, b1.z, b1.w};
#pragma unroll
            for (int i = 0; i < 4; ++i)
#pragma unroll
                for (int j = 0; j < 8; ++j) acc[i][j] += av[i] * bv[j];
        }
    }

#pragma unroll
    for (int i = 0; i < 4; ++i) {
        float bvv = 3.4e38f; int bc = 0;
#pragma unroll
        for (int j = 0; j < 8; ++j) {
            float d = scn[cg * 8 + j] - 2.0f * acc[i][j];
            if (d < bvv) { bvv = d; bc = cg * 8 + j; }
        }
        rv[pg * 4 + i][cg] = bvv;
        rc[pg * 4 + i][cg] = bc;
    }
    __syncthreads();
    if (t < BPTS) {
        float bvv = rv[t][0]; int bc = rc[t][0];
#pragma unroll
        for (int g = 1; g < 8; ++g) {
            float v = rv[t][g];
            if (v < bvv) { bvv = v; bc = rc[t][g]; }
        }
        lab[t] = bc;
    }
    __syncthreads();
    if (t < 384) {
        const int dgf = (t % 96) * 4;
        const int po  = t / 96;
#pragma unroll 2
        for (int r = 0; r < 64; ++r) {
            const int p = r * 4 + po;
            float4 v = *(const float4*)(CW + (size_t)lab[p] * DIM + dgf);
            *(float4*)(out + (size_t)(p0 + p) * DIM + dgf) = v;
        }
    }
}

extern "C" void kernel_launch(void* const* d_in, const int* in_sizes, int n_in,
                              void* d_out, int out_size, void* d_ws, size_t ws_size,
                              hipStream_t stream) {
    const float* x = (const float*)d_in[0];  // fp32 (16,4096,384)
    const float* W = (const float*)d_in[1];  // fp32 (384,384)
    const float* b = (const float*)d_in[2];  // fp32 (384,)
    float* out = (float*)d_out;              // fp32 (16,4096,384)

    float* centers = (float*)d_ws;                 // 64*384
    float* sums    = centers + KCL * DIM;          // 64*384
    float* cnorm   = sums + KCL * DIM;             // 64
    float* cnt     = cnorm + KCL;                  // 64
    float* CW      = cnt + KCL;                    // 64*384

    init_kernel<<<KCL, 384, 0, stream>>>(x, centers, sums, cnorm, cnt);
    for (int it = 0; it < ITERS; ++it) {
        fused_kernel<<<P_TOT / BPTS, 512, 0, stream>>>(x, centers, cnorm, sums, cnt);
        update_kernel<<<KCL, 384, 0, stream>>>(sums, cnt, centers, cnorm);
    }
    cw_kernel<<<KCL, 384, 0, stream>>>(centers, W, b, CW);
    final_kernel<<<P_TOT / BPTS, 512, 0, stream>>>(x, centers, cnorm, CW, out);
}

// Round 2
// 2259.953 us; speedup vs baseline: 1.0341x; 1.0341x over previous
//
#include <hip/hip_runtime.h>

#define P_TOT 65536
#define DIM   384
#define KCL   64
#define ITERS 10
#define BPTS  256          // points per block (assign / final)
#define APTS  256          // points per accum block
#define NSB   8            // partial sum buffers (atomic contention /8)
#define BK    16           // k-tile depth
#define NKT   (DIM / BK)   // 24
#define LDA   264          // padded A-tile row (points)
#define LDB   72           // padded B-tile row (clusters)

// d_ws layout (floats):
// centers[24576] | cnorm[64] | cnt[64] | CW[24576] | sums[8][24576]  ~= 983 KB
// labels (int[65536]) lives at the head of d_out (dead before final_kernel).

// centers0 = points[:64]; cnorm[c] = ||center||^2 ; zero cnt + all sum buffers
__global__ __launch_bounds__(384) void init_kernel(const float* __restrict__ x,
                                                   float* __restrict__ centers,
                                                   float* __restrict__ cnorm,
                                                   float* __restrict__ cnt,
                                                   float* __restrict__ sums) {
    __shared__ float red[384];
    const int c = blockIdx.x, t = threadIdx.x;
    float v = x[(size_t)c * DIM + t];
    centers[(size_t)c * DIM + t] = v;
#pragma unroll
    for (int b = 0; b < NSB; ++b) sums[(size_t)b * KCL * DIM + (size_t)c * DIM + t] = 0.f;
    if (t == 0) cnt[c] = 0.f;
    red[t] = v * v;
    __syncthreads();
    if (t < 128) red[t] = red[t] + red[t + 128] + red[t + 256];
    __syncthreads();
    for (int s = 64; s > 0; s >>= 1) {
        if (t < s) red[t] += red[t + s];
        __syncthreads();
    }
    if (t == 0) cnorm[c] = red[0];
}

// 256 points x 64 clusters GEMM (4pt x 8cl per thread), argmin -> labels[global].
// 41KB LDS -> 3 blocks/CU, register-prefetch double buffering.
__global__ __launch_bounds__(512) void assign_kernel(const float* __restrict__ x,
                                                     const float* __restrict__ centers,
                                                     const float* __restrict__ cnorm,
                                                     int* __restrict__ labels) {
    __shared__ float At[BK][LDA];         // transposed [k][point]
    __shared__ float Bt[BK][LDB];         // transposed [k][cluster]
    __shared__ float rv[BPTS][9];         // pad 9: conflict-free reduce
    __shared__ int   rc[BPTS][9];
    __shared__ float scn[KCL];

    const int t   = threadIdx.x;
    const int cg  = t & 7;          // cluster group: clusters cg*8..cg*8+7
    const int pg  = t >> 3;         // point group:   points  pg*4..pg*4+3
    const int p0  = blockIdx.x * BPTS;
    const int sp  = t >> 1;         // A-staging: point row 0..255
    const int sk  = (t & 1) * 8;    // A-staging: k offset {0,8}
    const int sc  = t >> 2;         // B-staging: cluster 0..63 (t<256)
    const int sck = (t & 3) * 4;    // B-staging: k offset {0,4,8,12}

    if (t < KCL) scn[t] = cnorm[t];

    float acc[4][8];
#pragma unroll
    for (int i = 0; i < 4; ++i)
#pragma unroll
        for (int j = 0; j < 8; ++j) acc[i][j] = 0.f;

    const float* xrow = x + (size_t)(p0 + sp) * DIM;
    const float* crow = centers + (size_t)sc * DIM;

    float4 ra0 = *(const float4*)(xrow + sk);
    float4 ra1 = *(const float4*)(xrow + sk + 4);
    float4 rb  = make_float4(0.f, 0.f, 0.f, 0.f);
    if (t < 256) rb = *(const float4*)(crow + sck);

    for (int kt = 0; kt < NKT; ++kt) {
        __syncthreads();
        At[sk + 0][sp] = ra0.x; At[sk + 1][sp] = ra0.y;
        At[sk + 2][sp] = ra0.z; At[sk + 3][sp] = ra0.w;
        At[sk + 4][sp] = ra1.x; At[sk + 5][sp] = ra1.y;
        At[sk + 6][sp] = ra1.z; At[sk + 7][sp] = ra1.w;
        if (t < 256) {
            Bt[sck + 0][sc] = rb.x; Bt[sck + 1][sc] = rb.y;
            Bt[sck + 2][sc] = rb.z; Bt[sck + 3][sc] = rb.w;
        }
        if (kt + 1 < NKT) {   // prefetch next tile; latency hides under kk-loop
            const int k0 = (kt + 1) * BK;
            ra0 = *(const float4*)(xrow + k0 + sk);
            ra1 = *(const float4*)(xrow + k0 + sk + 4);
            if (t < 256) rb = *(const float4*)(crow + k0 + sck);
        }
        __syncthreads();
#pragma unroll
        for (int kk = 0; kk < BK; ++kk) {
            float4 a4 = *(const float4*)&At[kk][pg * 4];
            float4 b0 = *(const float4*)&Bt[kk][cg * 8];
            float4 b1 = *(const float4*)&Bt[kk][cg * 8 + 4];
            const float av[4] = {a4.x, a4.y, a4.z, a4.w};
            const float bv[8] = {b0.x, b0.y, b0.z, b0.w, b1.x, b1.y, b1.z, b1.w};
#pragma unroll
            for (int i = 0; i < 4; ++i)
#pragma unroll
                for (int j = 0; j < 8; ++j) acc[i][j] += av[i] * bv[j];
        }
    }

#pragma unroll
    for (int i = 0; i < 4; ++i) {
        float bvv = 3.4e38f; int bc = 0;
#pragma unroll
        for (int j = 0; j < 8; ++j) {
            float d = scn[cg * 8 + j] - 2.0f * acc[i][j];
            if (d < bvv) { bvv = d; bc = cg * 8 + j; }  // strict <: lowest idx wins
        }
        rv[pg * 4 + i][cg] = bvv;
        rc[pg * 4 + i][cg] = bc;
    }
    __syncthreads();
    if (t < BPTS) {
        float bvv = rv[t][0]; int bc = rc[t][0];
#pragma unroll
        for (int g = 1; g < 8; ++g) {   // ascending cg: lowest cluster wins ties
            float v = rv[t][g];
            if (v < bvv) { bvv = v; bc = rc[t][g]; }
        }
        labels[p0 + t] = bc;
    }
}

// dim-parallel accumulation: thread t owns dim t. ds_add_f32 atomics (no RMW
// dependency chain), unroll 8 for load overlap. Flush to 1-of-8 partial
// buffers -> 8x less global atomic contention per address.
__global__ __launch_bounds__(384) void accum_kernel(const float* __restrict__ x,
                                                    const int* __restrict__ labels,
                                                    float* __restrict__ sums,
                                                    float* __restrict__ cnt) {
    __shared__ float lsum[KCL * DIM];   // 96 KB
    __shared__ int   llab[APTS];
    __shared__ int   lcnt[KCL];
    const int t = threadIdx.x;
    for (int i = t; i < KCL * DIM; i += 384) lsum[i] = 0.f;
    if (t < KCL) lcnt[t] = 0;
    const int p0 = blockIdx.x * APTS;
    if (t < APTS) llab[t] = labels[p0 + t];
    __syncthreads();
    if (t < APTS) atomicAdd(&lcnt[llab[t]], 1);

    const float* xp = x + (size_t)p0 * DIM + t;
#pragma unroll 8
    for (int i = 0; i < APTS; ++i) {
        atomicAdd(&lsum[llab[i] * DIM + t], xp[(size_t)i * DIM]);
    }
    __syncthreads();
    float* sb = sums + (size_t)(blockIdx.x & (NSB - 1)) * KCL * DIM;
    for (int i = t; i < KCL * DIM; i += 384) {
        float v = lsum[i];
        if (v != 0.f) atomicAdd(&sb[i], v);
    }
    if (t < KCL && lcnt[t] > 0) atomicAdd(&cnt[t], (float)lcnt[t]);
}

// centers[c] = cnt>0 ? sum(partials)/cnt : old ; cnorm ; re-zero partials/cnt
__global__ __launch_bounds__(384) void update_kernel(float* __restrict__ sums,
                                                     float* __restrict__ cnt,
                                                     float* __restrict__ centers,
                                                     float* __restrict__ cnorm) {
    __shared__ float red[384];
    const int c = blockIdx.x, t = threadIdx.x;
    float s = 0.f;
#pragma unroll
    for (int b = 0; b < NSB; ++b) {
        const size_t idx = (size_t)b * KCL * DIM + (size_t)c * DIM + t;
        s += sums[idx];
        sums[idx] = 0.f;
    }
    float n = cnt[c];
    float oldv = centers[(size_t)c * DIM + t];
    float nc = (n > 0.f) ? (s / n) : oldv;
    centers[(size_t)c * DIM + t] = nc;
    red[t] = nc * nc;
    __syncthreads();
    if (t == 0) cnt[c] = 0.f;   // after barrier: all reads of cnt[c] done
    if (t < 128) red[t] = red[t] + red[t + 128] + red[t + 256];
    __syncthreads();
    for (int st = 64; st > 0; st >>= 1) {
        if (t < st) red[t] += red[t + st];
        __syncthreads();
    }
    if (t == 0) cnorm[c] = red[0];
}

// CW[c][j] = b[j] + sum_d centers[c][d] * W[j][d]
__global__ __launch_bounds__(384) void cw_kernel(const float* __restrict__ centers,
                                                 const float* __restrict__ W,
                                                 const float* __restrict__ b,
                                                 float* __restrict__ CW) {
    __shared__ float cs[DIM];
    const int c = blockIdx.x, j = threadIdx.x;
    cs[j] = centers[(size_t)c * DIM + j];
    __syncthreads();
    float acc = b[j];
    const float* wr = W + (size_t)j * DIM;
    for (int d4 = 0; d4 < 96; ++d4) {
        float4 v = *(const float4*)(wr + d4 * 4);
        acc += cs[d4 * 4 + 0] * v.x + cs[d4 * 4 + 1] * v.y
             + cs[d4 * 4 + 2] * v.z + cs[d4 * 4 + 3] * v.w;
    }
    CW[(size_t)c * DIM + j] = acc;
}

// final: same GEMM/argmin schedule, then out[p][:] = CW[label[p]][:]
__global__ __launch_bounds__(512) void final_kernel(const float* __restrict__ x,
                                                    const float* __restrict__ centers,
                                                    const float* __restrict__ cnorm,
                                                    const float* __restrict__ CW,
                                                    float* __restrict__ out) {
    __shared__ float At[BK][LDA];
    __shared__ float Bt[BK][LDB];
    __shared__ float rv[BPTS][9];
    __shared__ int   rc[BPTS][9];
    __shared__ int   lab[BPTS];
    __shared__ float scn[KCL];

    const int t   = threadIdx.x;
    const int cg  = t & 7;
    const int pg  = t >> 3;
    const int p0  = blockIdx.x * BPTS;
    const int sp  = t >> 1;
    const int sk  = (t & 1) * 8;
    const int sc  = t >> 2;
    const int sck = (t & 3) * 4;

    if (t < KCL) scn[t] = cnorm[t];

    float acc[4][8];
#pragma unroll
    for (int i = 0; i < 4; ++i)
#pragma unroll
        for (int j = 0; j < 8; ++j) acc[i][j] = 0.f;

    const float* xrow = x + (size_t)(p0 + sp) * DIM;
    const float* crow = centers + (size_t)sc * DIM;

    float4 ra0 = *(const float4*)(xrow + sk);
    float4 ra1 = *(const float4*)(xrow + sk + 4);
    float4 rb  = make_float4(0.f, 0.f, 0.f, 0.f);
    if (t < 256) rb = *(const float4*)(crow + sck);

    for (int kt = 0; kt < NKT; ++kt) {
        __syncthreads();
        At[sk + 0][sp] = ra0.x; At[sk + 1][sp] = ra0.y;
        At[sk + 2][sp] = ra0.z; At[sk + 3][sp] = ra0.w;
        At[sk + 4][sp] = ra1.x; At[sk + 5][sp] = ra1.y;
        At[sk + 6][sp] = ra1.z; At[sk + 7][sp] = ra1.w;
        if (t < 256) {
            Bt[sck + 0][sc] = rb.x; Bt[sck + 1][sc] = rb.y;
            Bt[sck + 2][sc] = rb.z; Bt[sck + 3][sc] = rb.w;
        }
        if (kt + 1 < NKT) {
            const int k0 = (kt + 1) * BK;
            ra0 = *(const float4*)(xrow + k0 + sk);
            ra1 = *(const float4*)(xrow + k0 + sk + 4);
            if (t < 256) rb = *(const float4*)(crow + k0 + sck);
        }
        __syncthreads();
#pragma unroll
        for (int kk = 0; kk < BK; ++kk) {
            float4 a4 = *(const float4*)&At[kk][pg * 4];
            float4 b0 = *(const float4*)&Bt[kk][cg * 8];
            float4 b1 = *(const float4*)&Bt[kk][cg * 8 + 4];
            const float av[4] = {a4.x, a4.y, a4.z, a4.w};
            const float bv[8] = {b0.x, b0.y, b0.z, b0.w, b1.x, b1.y, b1.z, b1.w};
#pragma unroll
            for (int i = 0; i < 4; ++i)
#pragma unroll
                for (int j = 0; j < 8; ++j) acc[i][j] += av[i] * bv[j];
        }
    }

#pragma unroll
    for (int i = 0; i < 4; ++i) {
        float bvv = 3.4e38f; int bc = 0;
#pragma unroll
        for (int j = 0; j < 8; ++j) {
            float d = scn[cg * 8 + j] - 2.0f * acc[i][j];
            if (d < bvv) { bvv = d; bc = cg * 8 + j; }
        }
        rv[pg * 4 + i][cg] = bvv;
        rc[pg * 4 + i][cg] = bc;
    }
    __syncthreads();
    if (t < BPTS) {
        float bvv = rv[t][0]; int bc = rc[t][0];
#pragma unroll
        for (int g = 1; g < 8; ++g) {
            float v = rv[t][g];
            if (v < bvv) { bvv = v; bc = rc[t][g]; }
        }
        lab[t] = bc;
    }
    __syncthreads();
    if (t < 384) {
        const int dgf = (t % 96) * 4;
        const int po  = t / 96;
#pragma unroll 2
        for (int r = 0; r < 64; ++r) {
            const int p = r * 4 + po;
            float4 v = *(const float4*)(CW + (size_t)lab[p] * DIM + dgf);
            *(float4*)(out + (size_t)(p0 + p) * DIM + dgf) = v;
        }
    }
}

extern "C" void kernel_launch(void* const* d_in, const int* in_sizes, int n_in,
                              void* d_out, int out_size, void* d_ws, size_t ws_size,
                              hipStream_t stream) {
    const float* x = (const float*)d_in[0];  // fp32 (16,4096,384)
    const float* W = (const float*)d_in[1];  // fp32 (384,384)
    const float* b = (const float*)d_in[2];  // fp32 (384,)
    float* out = (float*)d_out;              // fp32 (16,4096,384)

    float* centers = (float*)d_ws;                 // 64*384
    float* cnorm   = centers + KCL * DIM;          // 64
    float* cnt     = cnorm + KCL;                  // 64
    float* CW      = cnt + KCL;                    // 64*384
    float* sums    = CW + KCL * DIM;               // 8 * 64*384
    int* labels = (int*)d_out;                     // head of d_out (dead before final)

    init_kernel<<<KCL, 384, 0, stream>>>(x, centers, cnorm, cnt, sums);
    for (int it = 0; it < ITERS; ++it) {
        assign_kernel<<<P_TOT / BPTS, 512, 0, stream>>>(x, centers, cnorm, labels);
        accum_kernel<<<P_TOT / APTS, 384, 0, stream>>>(x, labels, sums, cnt);
        update_kernel<<<KCL, 384, 0, stream>>>(sums, cnt, centers, cnorm);
    }
    cw_kernel<<<KCL, 384, 0, stream>>>(centers, W, b, CW);
    final_kernel<<<P_TOT / BPTS, 512, 0, stream>>>(x, centers, cnorm, CW, out);
}

// Round 3
// 1375.539 us; speedup vs baseline: 1.6990x; 1.6430x over previous
//
#include <hip/hip_runtime.h>

#define P_TOT 65536
#define DIM   384
#define KCL   64
#define ITERS 10
#define BPTS  256          // points per block (assign / final)
#define APTS  256          // points per accum block
#define NSB   8            // partial sum buffers (atomic contention /8)
#define BK    16           // k-tile depth
#define NKT   (DIM / BK)   // 24
#define LDA   260          // padded A row: %4==0 (b128 align), %8==4 (write banks)
#define LDB   68           // padded B row: same properties

// d_ws layout (floats):
// centers[24576] | cnorm[64] | cnt[64] | CW[24576] | sums[8][24576]  ~= 983 KB
// labels (int[65536]) lives at the head of d_out (dead before final_kernel).

// centers0 = points[:64]; cnorm[c] = ||center||^2 ; zero cnt + all sum buffers
__global__ __launch_bounds__(384) void init_kernel(const float* __restrict__ x,
                                                   float* __restrict__ centers,
                                                   float* __restrict__ cnorm,
                                                   float* __restrict__ cnt,
                                                   float* __restrict__ sums) {
    __shared__ float red[384];
    const int c = blockIdx.x, t = threadIdx.x;
    float v = x[(size_t)c * DIM + t];
    centers[(size_t)c * DIM + t] = v;
#pragma unroll
    for (int b = 0; b < NSB; ++b) sums[(size_t)b * KCL * DIM + (size_t)c * DIM + t] = 0.f;
    if (t == 0) cnt[c] = 0.f;
    red[t] = v * v;
    __syncthreads();
    if (t < 128) red[t] = red[t] + red[t + 128] + red[t + 256];
    __syncthreads();
    for (int s = 64; s > 0; s >>= 1) {
        if (t < s) red[t] += red[t + s];
        __syncthreads();
    }
    if (t == 0) cnorm[c] = red[0];
}

// 256 points x 64 clusters GEMM, 8pt x 8cl per thread (256 threads).
// 64 FMA per 4 ds_read_b128 -> LDS and VALU walls balanced.
// Same k accumulation order as previous version -> labels bit-identical.
__global__ __launch_bounds__(256) void assign_kernel(const float* __restrict__ x,
                                                     const float* __restrict__ centers,
                                                     const float* __restrict__ cnorm,
                                                     int* __restrict__ labels) {
    __shared__ float At[BK][LDA];         // transposed [k][point]
    __shared__ float Bt[BK][LDB];         // transposed [k][cluster]
    __shared__ float rv[BPTS][9];
    __shared__ int   rc[BPTS][9];
    __shared__ float scn[KCL];

    const int t    = threadIdx.x;
    const int cg   = t & 7;          // clusters cg*8..cg*8+7
    const int pg   = t >> 3;         // 0..31: points pg*8..pg*8+7
    const int p0   = blockIdx.x * BPTS;
    const int srow = t >> 2;         // 0..63 staging row
    const int skk  = (t & 3) * 4;    // k offset {0,4,8,12}

    if (t < KCL) scn[t] = cnorm[t];

    float acc[8][8];
#pragma unroll
    for (int i = 0; i < 8; ++i)
#pragma unroll
        for (int j = 0; j < 8; ++j) acc[i][j] = 0.f;

    const float* crow = centers + (size_t)srow * DIM;

    float4 ra[4], rb;
#pragma unroll
    for (int r = 0; r < 4; ++r)
        ra[r] = *(const float4*)(x + (size_t)(p0 + r * 64 + srow) * DIM + skk);
    rb = *(const float4*)(crow + skk);

    for (int kt = 0; kt < NKT; ++kt) {
        __syncthreads();
#pragma unroll
        for (int r = 0; r < 4; ++r) {
            At[skk + 0][r * 64 + srow] = ra[r].x;
            At[skk + 1][r * 64 + srow] = ra[r].y;
            At[skk + 2][r * 64 + srow] = ra[r].z;
            At[skk + 3][r * 64 + srow] = ra[r].w;
        }
        Bt[skk + 0][srow] = rb.x; Bt[skk + 1][srow] = rb.y;
        Bt[skk + 2][srow] = rb.z; Bt[skk + 3][srow] = rb.w;
        if (kt + 1 < NKT) {   // register prefetch of next tile
            const int k0 = (kt + 1) * BK;
#pragma unroll
            for (int r = 0; r < 4; ++r)
                ra[r] = *(const float4*)(x + (size_t)(p0 + r * 64 + srow) * DIM + k0 + skk);
            rb = *(const float4*)(crow + k0 + skk);
        }
        __syncthreads();
#pragma unroll
        for (int kk = 0; kk < BK; ++kk) {
            float4 a0 = *(const float4*)&At[kk][pg * 8];
            float4 a1 = *(const float4*)&At[kk][pg * 8 + 4];
            float4 b0 = *(const float4*)&Bt[kk][cg * 8];
            float4 b1 = *(const float4*)&Bt[kk][cg * 8 + 4];
            const float av[8] = {a0.x, a0.y, a0.z, a0.w, a1.x, a1.y, a1.z, a1.w};
            const float bv[8] = {b0.x, b0.y, b0.z, b0.w, b1.x, b1.y, b1.z, b1.w};
#pragma unroll
            for (int i = 0; i < 8; ++i)
#pragma unroll
                for (int j = 0; j < 8; ++j) acc[i][j] += av[i] * bv[j];
        }
    }

#pragma unroll
    for (int i = 0; i < 8; ++i) {
        float bvv = 3.4e38f; int bc = 0;
#pragma unroll
        for (int j = 0; j < 8; ++j) {
            float d = scn[cg * 8 + j] - 2.0f * acc[i][j];
            if (d < bvv) { bvv = d; bc = cg * 8 + j; }  // strict <: lowest idx wins
        }
        rv[pg * 8 + i][cg] = bvv;
        rc[pg * 8 + i][cg] = bc;
    }
    __syncthreads();
    {   // 256 threads reduce 256 points over 8 cluster groups (ascending ties)
        float bvv = rv[t][0]; int bc = rc[t][0];
#pragma unroll
        for (int g = 1; g < 8; ++g) {
            float v = rv[t][g];
            if (v < bvv) { bvv = v; bc = rc[t][g]; }
        }
        labels[p0 + t] = bc;
    }
}

// Counting-sort labels in LDS (3 KB), then register accumulation per cluster:
// thread t owns dim t; clusters' points are contiguous in order[] -> no LDS
// RMW table, no f32 LDS atomics, 4 independent partial accumulators.
__global__ __launch_bounds__(384) void accum_kernel(const float* __restrict__ x,
                                                    const int* __restrict__ labels,
                                                    float* __restrict__ sums,
                                                    float* __restrict__ cnt) {
    __shared__ int llab[APTS];
    __shared__ int lcnt[KCL];
    __shared__ int lstart[KCL + 1];
    __shared__ int lcur[KCL];
    __shared__ int order[APTS];
    const int t = threadIdx.x;
    const int p0 = blockIdx.x * APTS;
    if (t < KCL) lcnt[t] = 0;
    __syncthreads();
    int myl = -1;
    if (t < APTS) {
        myl = labels[p0 + t];
        llab[t] = myl;
        atomicAdd(&lcnt[myl], 1);       // int LDS atomic: native ds_add
    }
    __syncthreads();
    if (t < 64) {                       // wave 0: inclusive shfl scan over 64
        int v = lcnt[t];
        int s = v;
#pragma unroll
        for (int d = 1; d < 64; d <<= 1) {
            int u = __shfl_up(s, d, 64);
            if (t >= d) s += u;
        }
        lstart[t] = s - v;
        lcur[t] = s - v;
        if (t == 63) lstart[64] = s;
    }
    __syncthreads();
    if (t < APTS) {
        int pos = atomicAdd(&lcur[myl], 1);
        order[pos] = t;
    }
    __syncthreads();

    const float* xb = x + (size_t)p0 * DIM;
    float* sb = sums + (size_t)(blockIdx.x & (NSB - 1)) * KCL * DIM;
    // thread t owns dim t (blockDim == DIM)
    for (int c = 0; c < KCL; ++c) {
        const int s0 = lstart[c], e0 = lstart[c + 1];
        if (s0 == e0) continue;
        float a0 = 0.f, a1 = 0.f, a2 = 0.f, a3 = 0.f;
        int j = s0;
        for (; j + 3 < e0; j += 4) {
            a0 += xb[(size_t)order[j + 0] * DIM + t];
            a1 += xb[(size_t)order[j + 1] * DIM + t];
            a2 += xb[(size_t)order[j + 2] * DIM + t];
            a3 += xb[(size_t)order[j + 3] * DIM + t];
        }
        for (; j < e0; ++j) a0 += xb[(size_t)order[j] * DIM + t];
        atomicAdd(&sb[c * DIM + t], (a0 + a1) + (a2 + a3));
    }
    if (t < KCL && lcnt[t] > 0) atomicAdd(&cnt[t], (float)lcnt[t]);
}

// centers[c] = cnt>0 ? sum(partials)/cnt : old ; cnorm ; re-zero partials/cnt
__global__ __launch_bounds__(384) void update_kernel(float* __restrict__ sums,
                                                     float* __restrict__ cnt,
                                                     float* __restrict__ centers,
                                                     float* __restrict__ cnorm) {
    __shared__ float red[384];
    const int c = blockIdx.x, t = threadIdx.x;
    float s = 0.f;
#pragma unroll
    for (int b = 0; b < NSB; ++b) {
        const size_t idx = (size_t)b * KCL * DIM + (size_t)c * DIM + t;
        s += sums[idx];
        sums[idx] = 0.f;
    }
    float n = cnt[c];
    float oldv = centers[(size_t)c * DIM + t];
    float nc = (n > 0.f) ? (s / n) : oldv;
    centers[(size_t)c * DIM + t] = nc;
    red[t] = nc * nc;
    __syncthreads();
    if (t == 0) cnt[c] = 0.f;   // after barrier: all reads of cnt[c] done
    if (t < 128) red[t] = red[t] + red[t + 128] + red[t + 256];
    __syncthreads();
    for (int st = 64; st > 0; st >>= 1) {
        if (t < st) red[t] += red[t + st];
        __syncthreads();
    }
    if (t == 0) cnorm[c] = red[0];
}

// CW[c][j] = b[j] + sum_d centers[c][d] * W[j][d]
__global__ __launch_bounds__(384) void cw_kernel(const float* __restrict__ centers,
                                                 const float* __restrict__ W,
                                                 const float* __restrict__ b,
                                                 float* __restrict__ CW) {
    __shared__ float cs[DIM];
    const int c = blockIdx.x, j = threadIdx.x;
    cs[j] = centers[(size_t)c * DIM + j];
    __syncthreads();
    float acc = b[j];
    const float* wr = W + (size_t)j * DIM;
    for (int d4 = 0; d4 < 96; ++d4) {
        float4 v = *(const float4*)(wr + d4 * 4);
        acc += cs[d4 * 4 + 0] * v.x + cs[d4 * 4 + 1] * v.y
             + cs[d4 * 4 + 2] * v.z + cs[d4 * 4 + 3] * v.w;
    }
    CW[(size_t)c * DIM + j] = acc;
}

// final: proven 4x8 GEMM/argmin schedule (512 thr), then out[p][:] = CW[label[p]][:]
__global__ __launch_bounds__(512) void final_kernel(const float* __restrict__ x,
                                                    const float* __restrict__ centers,
                                                    const float* __restrict__ cnorm,
                                                    const float* __restrict__ CW,
                                                    float* __restrict__ out) {
    __shared__ float At[BK][LDA];
    __shared__ float Bt[BK][LDB];
    __shared__ float rv[BPTS][9];
    __shared__ int   rc[BPTS][9];
    __shared__ int   lab[BPTS];
    __shared__ float scn[KCL];

    const int t   = threadIdx.x;
    const int cg  = t & 7;
    const int pg  = t >> 3;
    const int p0  = blockIdx.x * BPTS;
    const int sp  = t >> 1;
    const int sk  = (t & 1) * 8;
    const int sc  = t >> 2;
    const int sck = (t & 3) * 4;

    if (t < KCL) scn[t] = cnorm[t];

    float acc[4][8];
#pragma unroll
    for (int i = 0; i < 4; ++i)
#pragma unroll
        for (int j = 0; j < 8; ++j) acc[i][j] = 0.f;

    const float* xrow = x + (size_t)(p0 + sp) * DIM;
    const float* crow = centers + (size_t)sc * DIM;

    float4 ra0 = *(const float4*)(xrow + sk);
    float4 ra1 = *(const float4*)(xrow + sk + 4);
    float4 rb  = make_float4(0.f, 0.f, 0.f, 0.f);
    if (t < 256) rb = *(const float4*)(crow + sck);

    for (int kt = 0; kt < NKT; ++kt) {
        __syncthreads();
        At[sk + 0][sp] = ra0.x; At[sk + 1][sp] = ra0.y;
        At[sk + 2][sp] = ra0.z; At[sk + 3][sp] = ra0.w;
        At[sk + 4][sp] = ra1.x; At[sk + 5][sp] = ra1.y;
        At[sk + 6][sp] = ra1.z; At[sk + 7][sp] = ra1.w;
        if (t < 256) {
            Bt[sck + 0][sc] = rb.x; Bt[sck + 1][sc] = rb.y;
            Bt[sck + 2][sc] = rb.z; Bt[sck + 3][sc] = rb.w;
        }
        if (kt + 1 < NKT) {
            const int k0 = (kt + 1) * BK;
            ra0 = *(const float4*)(xrow + k0 + sk);
            ra1 = *(const float4*)(xrow + k0 + sk + 4);
            if (t < 256) rb = *(const float4*)(crow + k0 + sck);
        }
        __syncthreads();
#pragma unroll
        for (int kk = 0; kk < BK; ++kk) {
            float4 a4 = *(const float4*)&At[kk][pg * 4];
            float4 b0 = *(const float4*)&Bt[kk][cg * 8];
            float4 b1 = *(const float4*)&Bt[kk][cg * 8 + 4];
            const float av[4] = {a4.x, a4.y, a4.z, a4.w};
            const float bv[8] = {b0.x, b0.y, b0.z, b0.w, b1.x, b1.y, b1.z, b1.w};
#pragma unroll
            for (int i = 0; i < 4; ++i)
#pragma unroll
                for (int j = 0; j < 8; ++j) acc[i][j] += av[i] * bv[j];
        }
    }

#pragma unroll
    for (int i = 0; i < 4; ++i) {
        float bvv = 3.4e38f; int bc = 0;
#pragma unroll
        for (int j = 0; j < 8; ++j) {
            float d = scn[cg * 8 + j] - 2.0f * acc[i][j];
            if (d < bvv) { bvv = d; bc = cg * 8 + j; }
        }
        rv[pg * 4 + i][cg] = bvv;
        rc[pg * 4 + i][cg] = bc;
    }
    __syncthreads();
    if (t < BPTS) {
        float bvv = rv[t][0]; int bc = rc[t][0];
#pragma unroll
        for (int g = 1; g < 8; ++g) {
            float v = rv[t][g];
            if (v < bvv) { bvv = v; bc = rc[t][g]; }
        }
        lab[t] = bc;
    }
    __syncthreads();
    if (t < 384) {
        const int dgf = (t % 96) * 4;
        const int po  = t / 96;
#pragma unroll 2
        for (int r = 0; r < 64; ++r) {
            const int p = r * 4 + po;
            float4 v = *(const float4*)(CW + (size_t)lab[p] * DIM + dgf);
            *(float4*)(out + (size_t)(p0 + p) * DIM + dgf) = v;
        }
    }
}

extern "C" void kernel_launch(void* const* d_in, const int* in_sizes, int n_in,
                              void* d_out, int out_size, void* d_ws, size_t ws_size,
                              hipStream_t stream) {
    const float* x = (const float*)d_in[0];  // fp32 (16,4096,384)
    const float* W = (const float*)d_in[1];  // fp32 (384,384)
    const float* b = (const float*)d_in[2];  // fp32 (384,)
    float* out = (float*)d_out;              // fp32 (16,4096,384)

    float* centers = (float*)d_ws;                 // 64*384
    float* cnorm   = centers + KCL * DIM;          // 64
    float* cnt     = cnorm + KCL;                  // 64
    float* CW      = cnt + KCL;                    // 64*384
    float* sums    = CW + KCL * DIM;               // 8 * 64*384
    int* labels = (int*)d_out;                     // head of d_out (dead before final)

    init_kernel<<<KCL, 384, 0, stream>>>(x, centers, cnorm, cnt, sums);
    for (int it = 0; it < ITERS; ++it) {
        assign_kernel<<<P_TOT / BPTS, 256, 0, stream>>>(x, centers, cnorm, labels);
        accum_kernel<<<P_TOT / APTS, 384, 0, stream>>>(x, labels, sums, cnt);
        update_kernel<<<KCL, 384, 0, stream>>>(sums, cnt, centers, cnorm);
    }
    cw_kernel<<<KCL, 384, 0, stream>>>(centers, W, b, CW);
    final_kernel<<<P_TOT / BPTS, 512, 0, stream>>>(x, centers, cnorm, CW, out);
}

// Round 4
// 1235.840 us; speedup vs baseline: 1.8911x; 1.1130x over previous
//
#include <hip/hip_runtime.h>

#define P_TOT 65536
#define DIM   384
#define KCL   64
#define ITERS 10
#define BPTS  256          // points per block (fused / label)
#define NSB   8            // partial sum buffers (atomic contention /8)
#define BK    32           // k-tile depth (double buffered, 1 barrier/tile)
#define NKT   (DIM / BK)   // 12
#define LDA   260          // padded A row: %4==0 (b128 align), %8==4 (write banks)
#define LDB   68           // padded B row

// d_ws layout (floats):
// centers[24576] | cnorm[64] | cnt[64] | CW[24576] | sums[8][24576]  ~= 983 KB
// final labels (int[65536] = 256KB) alias the sums area (dead after last update).

// centers0 = points[:64]; cnorm[c] = ||center||^2 ; zero cnt + all sum buffers
__global__ __launch_bounds__(384) void init_kernel(const float* __restrict__ x,
                                                   float* __restrict__ centers,
                                                   float* __restrict__ cnorm,
                                                   float* __restrict__ cnt,
                                                   float* __restrict__ sums) {
    __shared__ float red[384];
    const int c = blockIdx.x, t = threadIdx.x;
    float v = x[(size_t)c * DIM + t];
    centers[(size_t)c * DIM + t] = v;
#pragma unroll
    for (int b = 0; b < NSB; ++b) sums[(size_t)b * KCL * DIM + (size_t)c * DIM + t] = 0.f;
    if (t == 0) cnt[c] = 0.f;
    red[t] = v * v;
    __syncthreads();
    if (t < 128) red[t] = red[t] + red[t + 128] + red[t + 256];
    __syncthreads();
    for (int s = 64; s > 0; s >>= 1) {
        if (t < s) red[t] += red[t + s];
        __syncthreads();
    }
    if (t == 0) cnorm[c] = red[0];
}

// ---- shared GEMM+argmin macro-body (4pt x 8cl per thread, 512 thr, BK=32,
//      double-buffered LDS, one barrier per k-tile, shfl argmin). Produces
//      lab[BPTS] in LDS. K ascending => labels bit-identical to prior rounds.
#define GEMM_ARGMIN_BODY(X, CENTERS, CNORM)                                          \
    const int t   = threadIdx.x;                                                     \
    const int cg  = t & 7;                                                           \
    const int pg  = t >> 3;                                                          \
    const int p0  = blockIdx.x * BPTS;                                               \
    const int sar = t >> 1;          /* A staging row 0..255 */                      \
    const int sak = (t & 1) * 16;    /* A staging k offset {0,16} */                 \
    const int sbr = t >> 3;          /* B staging row 0..63 */                       \
    const int sbk = (t & 7) * 4;     /* B staging k offset {0..28} */                \
    if (t < KCL) scn[t] = (CNORM)[t];                                                \
    float acc[4][8];                                                                 \
    _Pragma("unroll")                                                                \
    for (int i = 0; i < 4; ++i)                                                      \
        _Pragma("unroll")                                                            \
        for (int j = 0; j < 8; ++j) acc[i][j] = 0.f;                                 \
    const float* xrow = (X) + (size_t)(p0 + sar) * DIM;                              \
    const float* crow = (CENTERS) + (size_t)sbr * DIM;                               \
    float4 ra0 = *(const float4*)(xrow + sak);                                       \
    float4 ra1 = *(const float4*)(xrow + sak + 4);                                   \
    float4 ra2 = *(const float4*)(xrow + sak + 8);                                   \
    float4 ra3 = *(const float4*)(xrow + sak + 12);                                  \
    float4 rb  = *(const float4*)(crow + sbk);                                       \
    for (int kt = 0; kt < NKT; ++kt) {                                               \
        const int cur = kt & 1;                                                      \
        At[cur][sak + 0][sar] = ra0.x;  At[cur][sak + 1][sar] = ra0.y;               \
        At[cur][sak + 2][sar] = ra0.z;  At[cur][sak + 3][sar] = ra0.w;               \
        At[cur][sak + 4][sar] = ra1.x;  At[cur][sak + 5][sar] = ra1.y;               \
        At[cur][sak + 6][sar] = ra1.z;  At[cur][sak + 7][sar] = ra1.w;               \
        At[cur][sak + 8][sar] = ra2.x;  At[cur][sak + 9][sar] = ra2.y;               \
        At[cur][sak + 10][sar] = ra2.z; At[cur][sak + 11][sar] = ra2.w;              \
        At[cur][sak + 12][sar] = ra3.x; At[cur][sak + 13][sar] = ra3.y;              \
        At[cur][sak + 14][sar] = ra3.z; At[cur][sak + 15][sar] = ra3.w;              \
        Bt[cur][sbk + 0][sbr] = rb.x;   Bt[cur][sbk + 1][sbr] = rb.y;                \
        Bt[cur][sbk + 2][sbr] = rb.z;   Bt[cur][sbk + 3][sbr] = rb.w;                \
        if (kt + 1 < NKT) {            /* prefetch next tile into regs */            \
            const int k0 = (kt + 1) * BK;                                            \
            ra0 = *(const float4*)(xrow + k0 + sak);                                 \
            ra1 = *(const float4*)(xrow + k0 + sak + 4);                             \
            ra2 = *(const float4*)(xrow + k0 + sak + 8);                             \
            ra3 = *(const float4*)(xrow + k0 + sak + 12);                            \
            rb  = *(const float4*)(crow + k0 + sbk);                                 \
        }                                                                            \
        __syncthreads();               /* single barrier per tile */                 \
        _Pragma("unroll")                                                            \
        for (int kk = 0; kk < BK; ++kk) {                                            \
            float4 a4 = *(const float4*)&At[cur][kk][pg * 4];                        \
            float4 b0 = *(const float4*)&Bt[cur][kk][cg * 8];                        \
            float4 b1 = *(const float4*)&Bt[cur][kk][cg * 8 + 4];                    \
            const float av[4] = {a4.x, a4.y, a4.z, a4.w};                            \
            const float bv[8] = {b0.x, b0.y, b0.z, b0.w, b1.x, b1.y, b1.z, b1.w};    \
            _Pragma("unroll")                                                        \
            for (int i = 0; i < 4; ++i)                                              \
                _Pragma("unroll")                                                    \
                for (int j = 0; j < 8; ++j) acc[i][j] += av[i] * bv[j];              \
        }                                                                            \
    }                                                                                \
    {                                                                                \
        float cn[8];                                                                 \
        _Pragma("unroll")                                                            \
        for (int j = 0; j < 8; ++j) cn[j] = scn[cg * 8 + j];                         \
        _Pragma("unroll")                                                            \
        for (int i = 0; i < 4; ++i) {                                                \
            float bvv = 3.4e38f; int bc = 0;                                         \
            _Pragma("unroll")                                                        \
            for (int j = 0; j < 8; ++j) {                                            \
                float d = cn[j] - 2.0f * acc[i][j];                                  \
                if (d < bvv) { bvv = d; bc = cg * 8 + j; }                           \
            }                                                                        \
            _Pragma("unroll")                                                        \
            for (int m = 1; m < 8; m <<= 1) {   /* reduce over 8 owner lanes */      \
                float ov = __shfl_xor(bvv, m, 64);                                   \
                int   oc = __shfl_xor(bc, m, 64);                                    \
                if (ov < bvv || (ov == bvv && oc < bc)) { bvv = ov; bc = oc; }       \
            }                                                                        \
            if (cg == 0) lab[pg * 4 + i] = bc;  /* lowest-index tie win */           \
        }                                                                            \
    }                                                                                \
    __syncthreads();

// Fused assign + accumulate: GEMM/argmin (labels stay in LDS), counting sort,
// register accumulation over L2-warm x rows, flush to NSB partial buffers.
__global__ __launch_bounds__(512) void fused_kernel(const float* __restrict__ x,
                                                    const float* __restrict__ centers,
                                                    const float* __restrict__ cnorm,
                                                    float* __restrict__ sums,
                                                    float* __restrict__ cnt) {
    __shared__ float At[2][BK][LDA];   // 66.6 KB
    __shared__ float Bt[2][BK][LDB];   // 17.4 KB
    __shared__ float scn[KCL];
    __shared__ int   lab[BPTS];
    __shared__ int   lcnt[KCL];
    __shared__ int   lstart[KCL + 1];
    __shared__ int   lcur[KCL];
    __shared__ int   order[BPTS];

    if (threadIdx.x < KCL) lcnt[threadIdx.x] = 0;

    GEMM_ARGMIN_BODY(x, centers, cnorm)

    int myl = -1;
    if (t < BPTS) {
        myl = lab[t];
        atomicAdd(&lcnt[myl], 1);            // native int LDS atomic
    }
    __syncthreads();
    if (t < 64) {                            // wave 0: inclusive shfl scan
        int v = lcnt[t];
        int s = v;
#pragma unroll
        for (int d = 1; d < 64; d <<= 1) {
            int u = __shfl_up(s, d, 64);
            if (t >= d) s += u;
        }
        lstart[t] = s - v;
        lcur[t] = s - v;
        if (t == 63) lstart[64] = s;
    }
    __syncthreads();
    if (t < BPTS) {
        int pos = atomicAdd(&lcur[myl], 1);
        order[pos] = t;
    }
    __syncthreads();

    if (t < DIM) {                           // thread t owns dim t (t<384)
        const float* xb = x + (size_t)p0 * DIM;
        float* sb = sums + (size_t)(blockIdx.x & (NSB - 1)) * KCL * DIM;
        for (int c = 0; c < KCL; ++c) {
            const int s0 = lstart[c], e0 = lstart[c + 1];
            if (s0 == e0) continue;
            float a0 = 0.f, a1 = 0.f, a2 = 0.f, a3 = 0.f;
            int j = s0;
            for (; j + 3 < e0; j += 4) {     // L2-warm rows, loads pipeline
                a0 += xb[(size_t)order[j + 0] * DIM + t];
                a1 += xb[(size_t)order[j + 1] * DIM + t];
                a2 += xb[(size_t)order[j + 2] * DIM + t];
                a3 += xb[(size_t)order[j + 3] * DIM + t];
            }
            for (; j < e0; ++j) a0 += xb[(size_t)order[j] * DIM + t];
            atomicAdd(&sb[c * DIM + t], (a0 + a1) + (a2 + a3));
        }
    }
    if (t < KCL && lcnt[t] > 0) atomicAdd(&cnt[t], (float)lcnt[t]);
}

// labels for the final pass -> global (ws sums area, dead after last update)
__global__ __launch_bounds__(512) void label_kernel(const float* __restrict__ x,
                                                    const float* __restrict__ centers,
                                                    const float* __restrict__ cnorm,
                                                    int* __restrict__ labs) {
    __shared__ float At[2][BK][LDA];
    __shared__ float Bt[2][BK][LDB];
    __shared__ float scn[KCL];
    __shared__ int   lab[BPTS];

    GEMM_ARGMIN_BODY(x, centers, cnorm)

    if (t < BPTS) labs[p0 + t] = lab[t];
}

// centers[c] = cnt>0 ? sum(partials)/cnt : old ; cnorm ; re-zero partials/cnt
__global__ __launch_bounds__(384) void update_kernel(float* __restrict__ sums,
                                                     float* __restrict__ cnt,
                                                     float* __restrict__ centers,
                                                     float* __restrict__ cnorm) {
    __shared__ float red[384];
    const int c = blockIdx.x, t = threadIdx.x;
    float s = 0.f;
#pragma unroll
    for (int b = 0; b < NSB; ++b) {
        const size_t idx = (size_t)b * KCL * DIM + (size_t)c * DIM + t;
        s += sums[idx];
        sums[idx] = 0.f;
    }
    float n = cnt[c];
    float oldv = centers[(size_t)c * DIM + t];
    float nc = (n > 0.f) ? (s / n) : oldv;
    centers[(size_t)c * DIM + t] = nc;
    red[t] = nc * nc;
    __syncthreads();
    if (t == 0) cnt[c] = 0.f;   // after barrier: all reads of cnt[c] done
    if (t < 128) red[t] = red[t] + red[t + 128] + red[t + 256];
    __syncthreads();
    for (int st = 64; st > 0; st >>= 1) {
        if (t < st) red[t] += red[t + st];
        __syncthreads();
    }
    if (t == 0) cnorm[c] = red[0];
}

// CW[c][j] = b[j] + sum_d centers[c][d] * W[j][d]
__global__ __launch_bounds__(384) void cw_kernel(const float* __restrict__ centers,
                                                 const float* __restrict__ W,
                                                 const float* __restrict__ b,
                                                 float* __restrict__ CW) {
    __shared__ float cs[DIM];
    const int c = blockIdx.x, j = threadIdx.x;
    cs[j] = centers[(size_t)c * DIM + j];
    __syncthreads();
    float acc = b[j];
    const float* wr = W + (size_t)j * DIM;
    for (int d4 = 0; d4 < 96; ++d4) {
        float4 v = *(const float4*)(wr + d4 * 4);
        acc += cs[d4 * 4 + 0] * v.x + cs[d4 * 4 + 1] * v.y
             + cs[d4 * 4 + 2] * v.z + cs[d4 * 4 + 3] * v.w;
    }
    CW[(size_t)c * DIM + j] = acc;
}

// pure-BW gather: out[p][:] = CW[labs[p]][:]. 2048 blocks x 256 thr, 32 rows/blk.
__global__ __launch_bounds__(256) void gather_kernel(const int* __restrict__ labs,
                                                     const float* __restrict__ CW,
                                                     float* __restrict__ out) {
    __shared__ int lab[32];
    const int t = threadIdx.x;
    const int p0 = blockIdx.x * 32;
    if (t < 32) lab[t] = labs[p0 + t];
    __syncthreads();
    const int pp = t >> 3;           // 0..31: row
    const int j0 = t & 7;            // 8 threads per row
    const float* src = CW + (size_t)lab[pp] * DIM;
    float* dst = out + (size_t)(p0 + pp) * DIM;
#pragma unroll
    for (int r = 0; r < 12; ++r) {
        const int jg = (r * 8 + j0) * 4;
        *(float4*)(dst + jg) = *(const float4*)(src + jg);
    }
}

extern "C" void kernel_launch(void* const* d_in, const int* in_sizes, int n_in,
                              void* d_out, int out_size, void* d_ws, size_t ws_size,
                              hipStream_t stream) {
    const float* x = (const float*)d_in[0];  // fp32 (16,4096,384)
    const float* W = (const float*)d_in[1];  // fp32 (384,384)
    const float* b = (const float*)d_in[2];  // fp32 (384,)
    float* out = (float*)d_out;              // fp32 (16,4096,384)

    float* centers = (float*)d_ws;                 // 64*384
    float* cnorm   = centers + KCL * DIM;          // 64
    float* cnt     = cnorm + KCL;                  // 64
    float* CW      = cnt + KCL;                    // 64*384
    float* sums    = CW + KCL * DIM;               // 8 * 64*384
    int* labs      = (int*)sums;                   // aliases sums (dead after loop)

    init_kernel<<<KCL, 384, 0, stream>>>(x, centers, cnorm, cnt, sums);
    for (int it = 0; it < ITERS; ++it) {
        fused_kernel<<<P_TOT / BPTS, 512, 0, stream>>>(x, centers, cnorm, sums, cnt);
        update_kernel<<<KCL, 384, 0, stream>>>(sums, cnt, centers, cnorm);
    }
    cw_kernel<<<KCL, 384, 0, stream>>>(centers, W, b, CW);
    label_kernel<<<P_TOT / BPTS, 512, 0, stream>>>(x, centers, cnorm, labs);
    gather_kernel<<<P_TOT / 32, 256, 0, stream>>>(labs, CW, out);
}

// Round 5
// 1226.785 us; speedup vs baseline: 1.9051x; 1.0074x over previous
//
#include <hip/hip_runtime.h>

#define P_TOT 65536
#define DIM   384
#define KCL   64
#define ITERS 10
#define BPTS  128          // points per block (fused / label) -> grid 512 = 2 blocks/CU
#define NSB   8            // partial sum buffers (atomic contention /8)
#define BK    32           // k-tile depth (double buffered, 1 barrier/tile)
#define NKT   (DIM / BK)   // 12
#define LDA   128          // unpadded: reads broadcast, writes 2-way (free)
#define LDB   68           // padded B row

// d_ws layout (floats):
// centers[24576] | cnorm[64] | cnt[64] | CW[24576] | sums[8][24576]  ~= 983 KB
// final labels (int[65536] = 256KB) alias the sums area (dead after last update).

// centers0 = points[:64]; cnorm[c] = ||center||^2 ; zero cnt + all sum buffers
__global__ __launch_bounds__(384) void init_kernel(const float* __restrict__ x,
                                                   float* __restrict__ centers,
                                                   float* __restrict__ cnorm,
                                                   float* __restrict__ cnt,
                                                   float* __restrict__ sums) {
    __shared__ float red[384];
    const int c = blockIdx.x, t = threadIdx.x;
    float v = x[(size_t)c * DIM + t];
    centers[(size_t)c * DIM + t] = v;
#pragma unroll
    for (int b = 0; b < NSB; ++b) sums[(size_t)b * KCL * DIM + (size_t)c * DIM + t] = 0.f;
    if (t == 0) cnt[c] = 0.f;
    red[t] = v * v;
    __syncthreads();
    if (t < 128) red[t] = red[t] + red[t + 128] + red[t + 256];
    __syncthreads();
    for (int s = 64; s > 0; s >>= 1) {
        if (t < s) red[t] += red[t + s];
        __syncthreads();
    }
    if (t == 0) cnorm[c] = red[0];
}

// ---- shared GEMM+argmin body: 128 points x 64 clusters, 512 threads,
//      4pt x 4cl per thread, BK=32 double-buffered, 1 barrier/tile.
//      K ascending, one FMA per k => distances bit-identical to prior rounds.
//      Produces lab[BPTS] in LDS.
#define GEMM_ARGMIN_BODY(X, CENTERS, CNORM)                                          \
    const int t    = threadIdx.x;                                                    \
    const int cg   = t & 15;         /* clusters cg*4..cg*4+3 */                     \
    const int pg   = t >> 4;         /* 0..31: points pg*4..pg*4+3 */                \
    const int p0   = blockIdx.x * BPTS;                                              \
    const int sar  = t >> 2;         /* A staging row 0..127 */                      \
    const int sak  = (t & 3) * 4;    /* A staging k offset {0,4,8,12} (+16) */       \
    const int sbr  = t >> 3;         /* B staging row 0..63 */                       \
    const int sbk  = (t & 7) * 4;    /* B staging k offset {0..28} */                \
    if (t < KCL) scn[t] = (CNORM)[t];                                                \
    float acc[4][4];                                                                 \
    _Pragma("unroll")                                                                \
    for (int i = 0; i < 4; ++i)                                                      \
        _Pragma("unroll")                                                            \
        for (int j = 0; j < 4; ++j) acc[i][j] = 0.f;                                 \
    const float* xrow = (X) + (size_t)(p0 + sar) * DIM;                              \
    const float* crow = (CENTERS) + (size_t)sbr * DIM;                               \
    float4 ra0 = *(const float4*)(xrow + sak);                                       \
    float4 ra1 = *(const float4*)(xrow + sak + 16);                                  \
    float4 rb  = *(const float4*)(crow + sbk);                                       \
    for (int kt = 0; kt < NKT; ++kt) {                                               \
        const int cur = kt & 1;                                                      \
        At[cur][sak + 0][sar] = ra0.x;  At[cur][sak + 1][sar] = ra0.y;               \
        At[cur][sak + 2][sar] = ra0.z;  At[cur][sak + 3][sar] = ra0.w;               \
        At[cur][sak + 16][sar] = ra1.x; At[cur][sak + 17][sar] = ra1.y;              \
        At[cur][sak + 18][sar] = ra1.z; At[cur][sak + 19][sar] = ra1.w;              \
        Bt[cur][sbk + 0][sbr] = rb.x;   Bt[cur][sbk + 1][sbr] = rb.y;                \
        Bt[cur][sbk + 2][sbr] = rb.z;   Bt[cur][sbk + 3][sbr] = rb.w;                \
        if (kt + 1 < NKT) {            /* prefetch next tile into regs */            \
            const int k0 = (kt + 1) * BK;                                            \
            ra0 = *(const float4*)(xrow + k0 + sak);                                 \
            ra1 = *(const float4*)(xrow + k0 + sak + 16);                            \
            rb  = *(const float4*)(crow + k0 + sbk);                                 \
        }                                                                            \
        __syncthreads();               /* single barrier per tile */                 \
        _Pragma("unroll")                                                            \
        for (int kk = 0; kk < BK; ++kk) {                                            \
            float4 a4 = *(const float4*)&At[cur][kk][pg * 4];                        \
            float4 b4 = *(const float4*)&Bt[cur][kk][cg * 4];                        \
            const float av[4] = {a4.x, a4.y, a4.z, a4.w};                            \
            const float bv[4] = {b4.x, b4.y, b4.z, b4.w};                            \
            _Pragma("unroll")                                                        \
            for (int i = 0; i < 4; ++i)                                              \
                _Pragma("unroll")                                                    \
                for (int j = 0; j < 4; ++j) acc[i][j] += av[i] * bv[j];              \
        }                                                                            \
    }                                                                                \
    {                                                                                \
        float cn[4];                                                                 \
        _Pragma("unroll")                                                            \
        for (int j = 0; j < 4; ++j) cn[j] = scn[cg * 4 + j];                         \
        _Pragma("unroll")                                                            \
        for (int i = 0; i < 4; ++i) {                                                \
            float bvv = 3.4e38f; int bc = 0;                                         \
            _Pragma("unroll")                                                        \
            for (int j = 0; j < 4; ++j) {                                            \
                float d = cn[j] - 2.0f * acc[i][j];                                  \
                if (d < bvv) { bvv = d; bc = cg * 4 + j; }                           \
            }                                                                        \
            _Pragma("unroll")                                                        \
            for (int m = 1; m < 16; m <<= 1) {  /* reduce over 16 owner lanes */     \
                float ov = __shfl_xor(bvv, m, 64);                                   \
                int   oc = __shfl_xor(bc, m, 64);                                    \
                if (ov < bvv || (ov == bvv && oc < bc)) { bvv = ov; bc = oc; }       \
            }                                                                        \
            if (cg == 0) lab[pg * 4 + i] = bc;  /* lowest-index tie win */           \
        }                                                                            \
    }                                                                                \
    __syncthreads();

// Fused assign + accumulate: GEMM/argmin (labels stay in LDS), counting sort,
// sorted-segment register accumulation over cache-warm x rows, flush to NSB
// partial buffers. ~52KB LDS -> 2 blocks/CU at grid 512: phases overlap
// across co-resident blocks.
__global__ __launch_bounds__(512, 4) void fused_kernel(const float* __restrict__ x,
                                                       const float* __restrict__ centers,
                                                       const float* __restrict__ cnorm,
                                                       float* __restrict__ sums,
                                                       float* __restrict__ cnt) {
    __shared__ float At[2][BK][LDA];   // 32 KB
    __shared__ float Bt[2][BK][LDB];   // 17.4 KB
    __shared__ float scn[KCL];
    __shared__ int   lab[BPTS];
    __shared__ int   lcnt[KCL];
    __shared__ int   lstart[KCL + 1];
    __shared__ int   lcur[KCL];
    __shared__ int   order[BPTS];

    if (threadIdx.x < KCL) lcnt[threadIdx.x] = 0;

    GEMM_ARGMIN_BODY(x, centers, cnorm)

    int myl = -1;
    if (t < BPTS) {
        myl = lab[t];
        atomicAdd(&lcnt[myl], 1);            // native int LDS atomic
    }
    __syncthreads();
    if (t < 64) {                            // wave 0: inclusive shfl scan
        int v = lcnt[t];
        int s = v;
#pragma unroll
        for (int d = 1; d < 64; d <<= 1) {
            int u = __shfl_up(s, d, 64);
            if (t >= d) s += u;
        }
        lstart[t] = s - v;
        lcur[t] = s - v;
        if (t == 63) lstart[64] = s;
    }
    __syncthreads();
    if (t < BPTS) {
        int pos = atomicAdd(&lcur[myl], 1);
        order[pos] = t;
    }
    __syncthreads();

    if (t < DIM) {                           // thread t owns dim t (t<384)
        const float* xb = x + (size_t)p0 * DIM;
        float* sb = sums + (size_t)(blockIdx.x & (NSB - 1)) * KCL * DIM;
        // single sorted-segment walk: run accumulator, flush on cluster change.
        // order[]/lab[] reads are wave-uniform (broadcast); branch is uniform.
        int   curc = lab[order[0]];
        float run  = 0.f;
        for (int j = 0; j < BPTS; ++j) {
            const int p = order[j];
            const int c = lab[p];
            if (c != curc) {
                atomicAdd(&sb[curc * DIM + t], run);
                run = 0.f;
                curc = c;
            }
            run += xb[(size_t)p * DIM + t];
        }
        atomicAdd(&sb[curc * DIM + t], run);
    }
    if (t < KCL && lcnt[t] > 0) atomicAdd(&cnt[t], (float)lcnt[t]);
}

// labels for the final pass -> global (ws sums area, dead after last update)
__global__ __launch_bounds__(512, 4) void label_kernel(const float* __restrict__ x,
                                                       const float* __restrict__ centers,
                                                       const float* __restrict__ cnorm,
                                                       int* __restrict__ labs) {
    __shared__ float At[2][BK][LDA];
    __shared__ float Bt[2][BK][LDB];
    __shared__ float scn[KCL];
    __shared__ int   lab[BPTS];

    GEMM_ARGMIN_BODY(x, centers, cnorm)

    if (t < BPTS) labs[p0 + t] = lab[t];
}

// centers[c] = cnt>0 ? sum(partials)/cnt : old ; cnorm ; re-zero partials/cnt
__global__ __launch_bounds__(384) void update_kernel(float* __restrict__ sums,
                                                     float* __restrict__ cnt,
                                                     float* __restrict__ centers,
                                                     float* __restrict__ cnorm) {
    __shared__ float red[384];
    const int c = blockIdx.x, t = threadIdx.x;
    float s = 0.f;
#pragma unroll
    for (int b = 0; b < NSB; ++b) {
        const size_t idx = (size_t)b * KCL * DIM + (size_t)c * DIM + t;
        s += sums[idx];
        sums[idx] = 0.f;
    }
    float n = cnt[c];
    float oldv = centers[(size_t)c * DIM + t];
    float nc = (n > 0.f) ? (s / n) : oldv;
    centers[(size_t)c * DIM + t] = nc;
    red[t] = nc * nc;
    __syncthreads();
    if (t == 0) cnt[c] = 0.f;   // after barrier: all reads of cnt[c] done
    if (t < 128) red[t] = red[t] + red[t + 128] + red[t + 256];
    __syncthreads();
    for (int st = 64; st > 0; st >>= 1) {
        if (t < st) red[t] += red[t + st];
        __syncthreads();
    }
    if (t == 0) cnorm[c] = red[0];
}

// CW[c][j] = b[j] + sum_d centers[c][d] * W[j][d]
__global__ __launch_bounds__(384) void cw_kernel(const float* __restrict__ centers,
                                                 const float* __restrict__ W,
                                                 const float* __restrict__ b,
                                                 float* __restrict__ CW) {
    __shared__ float cs[DIM];
    const int c = blockIdx.x, j = threadIdx.x;
    cs[j] = centers[(size_t)c * DIM + j];
    __syncthreads();
    float acc = b[j];
    const float* wr = W + (size_t)j * DIM;
    for (int d4 = 0; d4 < 96; ++d4) {
        float4 v = *(const float4*)(wr + d4 * 4);
        acc += cs[d4 * 4 + 0] * v.x + cs[d4 * 4 + 1] * v.y
             + cs[d4 * 4 + 2] * v.z + cs[d4 * 4 + 3] * v.w;
    }
    CW[(size_t)c * DIM + j] = acc;
}

// pure-BW gather: out[p][:] = CW[labs[p]][:]. 2048 blocks x 256 thr, 32 rows/blk.
__global__ __launch_bounds__(256) void gather_kernel(const int* __restrict__ labs,
                                                     const float* __restrict__ CW,
                                                     float* __restrict__ out) {
    __shared__ int lab[32];
    const int t = threadIdx.x;
    const int p0 = blockIdx.x * 32;
    if (t < 32) lab[t] = labs[p0 + t];
    __syncthreads();
    const int pp = t >> 3;           // 0..31: row
    const int j0 = t & 7;            // 8 threads per row
    const float* src = CW + (size_t)lab[pp] * DIM;
    float* dst = out + (size_t)(p0 + pp) * DIM;
#pragma unroll
    for (int r = 0; r < 12; ++r) {
        const int jg = (r * 8 + j0) * 4;
        *(float4*)(dst + jg) = *(const float4*)(src + jg);
    }
}

extern "C" void kernel_launch(void* const* d_in, const int* in_sizes, int n_in,
                              void* d_out, int out_size, void* d_ws, size_t ws_size,
                              hipStream_t stream) {
    const float* x = (const float*)d_in[0];  // fp32 (16,4096,384)
    const float* W = (const float*)d_in[1];  // fp32 (384,384)
    const float* b = (const float*)d_in[2];  // fp32 (384,)
    float* out = (float*)d_out;              // fp32 (16,4096,384)

    float* centers = (float*)d_ws;                 // 64*384
    float* cnorm   = centers + KCL * DIM;          // 64
    float* cnt     = cnorm + KCL;                  // 64
    float* CW      = cnt + KCL;                    // 64*384
    float* sums    = CW + KCL * DIM;               // 8 * 64*384
    int* labs      = (int*)sums;                   // aliases sums (dead after loop)

    init_kernel<<<KCL, 384, 0, stream>>>(x, centers, cnorm, cnt, sums);
    for (int it = 0; it < ITERS; ++it) {
        fused_kernel<<<P_TOT / BPTS, 512, 0, stream>>>(x, centers, cnorm, sums, cnt);
        update_kernel<<<KCL, 384, 0, stream>>>(sums, cnt, centers, cnorm);
    }
    cw_kernel<<<KCL, 384, 0, stream>>>(centers, W, b, CW);
    label_kernel<<<P_TOT / BPTS, 512, 0, stream>>>(x, centers, cnorm, labs);
    gather_kernel<<<P_TOT / 32, 256, 0, stream>>>(labs, CW, out);
}